// Round 3
// baseline (447.015 us; speedup 1.0000x reference)
//
#include <hip/hip_runtime.h>
#include <hip/hip_bf16.h>

#define DG 16384
#define NNZ 262144
#define BB 128

typedef __attribute__((ext_vector_type(8))) short bf16x8;
typedef __attribute__((ext_vector_type(4))) float f32x4;
typedef __attribute__((ext_vector_type(4))) unsigned short us4;

// ---- workspace layout (bytes) ----
#define WS_ROWPTR 0            // 16385 ints
#define WS_XIN16  66048        // 128*16384 bf16
#define WS_T      4260352      // 6 * 16384*128*4 fp32 planes
#define WS_XPOOL  54592000     // 128*65536 bf16
#define WS_XB0    71369216     // 16384*128 bf16 shadow plane A
#define WS_XB1    75563520     // 16384*128 bf16 shadow plane B
#define WS_XNN1B  79757824     // 128*512 bf16
#define WS_DEC2   79888896     // 128*512 bf16
#define WS_XNN2   80019968     // 128*256 fp32
#define WS_HIDB   80151040     // 128*512 bf16
#define WS_N1     80282112     // 256*4
#define WS_TAIL   80283136     // 128*4
#define WS_PART1  81000448     // nn1 partials: 64*65536*4 = 16.8MB
#define WS_PART2  98000384     // fc1 partials: 128*65536*4 = 33.5MB

__device__ __forceinline__ unsigned short f2bf(float f) {
  __hip_bfloat16 h = __float2bfloat16(f);
  return __builtin_bit_cast(unsigned short, h);
}
__device__ __forceinline__ float bf2f(unsigned short u) {
  return __builtin_bit_cast(float, (unsigned)u << 16);
}
__device__ __forceinline__ f32x4 ntload4(const float* p) {
  return __builtin_nontemporal_load((const f32x4*)p);
}

// ---- prep: rowptr binary search + x_in -> bf16 [128,16384] ----
__global__ __launch_bounds__(256) void prep_kernel(
    const float* __restrict__ x_in, const int* __restrict__ rows,
    int* __restrict__ rowptr, unsigned short* __restrict__ xin16) {
  int idx = blockIdx.x * 256 + threadIdx.x;   // 524288 threads
  if (idx <= DG) {
    int lo = 0, hi = NNZ;
    while (lo < hi) { int mid = (lo + hi) >> 1; if (rows[mid] < idx) lo = mid + 1; else hi = mid; }
    rowptr[idx] = lo;
  }
  f32x4 v = ((const f32x4*)x_in)[idx];
  us4 o; o[0] = f2bf(v[0]); o[1] = f2bf(v[1]); o[2] = f2bf(v[2]); o[3] = f2bf(v[3]);
  ((us4*)xin16)[idx] = o;
}

// ---- transpose x_in [128,16384] -> T0 [16384,128] fp32 + bf16 shadow ----
__global__ __launch_bounds__(1024) void transpose_kernel(
    const float* __restrict__ x_in, float* __restrict__ T0,
    unsigned short* __restrict__ Xb0) {
  __shared__ float t[32][33];
  int v0 = blockIdx.x * 32, b0 = blockIdx.y * 32;
  t[threadIdx.y][threadIdx.x] = x_in[(size_t)(b0 + threadIdx.y) * DG + v0 + threadIdx.x];
  __syncthreads();
  float v = t[threadIdx.x][threadIdx.y];
  size_t o = (size_t)(v0 + threadIdx.y) * BB + b0 + threadIdx.x;
  T0[o] = v;
  Xb0[o] = f2bf(v);
}

// ---- CSR SpMM (bf16 gather) + Chebyshev: out = scale*L@Xb - prev; 2 rows/block ----
__global__ __launch_bounds__(256) void spmm2(
    const int* __restrict__ rowptr, const int* __restrict__ cols,
    const float* __restrict__ vals, const unsigned short* __restrict__ Xb,
    const float* __restrict__ Tprev, float* __restrict__ Tout,
    unsigned short* __restrict__ Xbout, float scale) {
  int r = blockIdx.x * 2 + (threadIdx.x >> 7);
  int b = threadIdx.x & 127;
  int e0 = rowptr[r], e1 = rowptr[r + 1];
  float acc0 = 0.f, acc1 = 0.f;
  int e = e0;
  for (; e + 8 <= e1; e += 8) {
    int c0 = cols[e], c1 = cols[e + 1], c2 = cols[e + 2], c3 = cols[e + 3];
    int c4 = cols[e + 4], c5 = cols[e + 5], c6 = cols[e + 6], c7 = cols[e + 7];
    float v0 = vals[e], v1 = vals[e + 1], v2 = vals[e + 2], v3 = vals[e + 3];
    float v4 = vals[e + 4], v5 = vals[e + 5], v6 = vals[e + 6], v7 = vals[e + 7];
    float x0 = bf2f(Xb[(size_t)c0 * BB + b]), x1 = bf2f(Xb[(size_t)c1 * BB + b]);
    float x2 = bf2f(Xb[(size_t)c2 * BB + b]), x3 = bf2f(Xb[(size_t)c3 * BB + b]);
    float x4 = bf2f(Xb[(size_t)c4 * BB + b]), x5 = bf2f(Xb[(size_t)c5 * BB + b]);
    float x6 = bf2f(Xb[(size_t)c6 * BB + b]), x7 = bf2f(Xb[(size_t)c7 * BB + b]);
    acc0 += v0 * x0; acc1 += v1 * x1; acc0 += v2 * x2; acc1 += v3 * x3;
    acc0 += v4 * x4; acc1 += v5 * x5; acc0 += v6 * x6; acc1 += v7 * x7;
  }
  for (; e < e1; ++e) acc0 += vals[e] * bf2f(Xb[(size_t)cols[e] * BB + b]);
  float out = scale * (acc0 + acc1);
  size_t o = (size_t)r * BB + b;
  if (Tprev) out -= Tprev[o];
  Tout[o] = out;
  Xbout[o] = f2bf(out);
}

// ---- fused Cheby-combine + bias + ReLU + MaxPool(8) -> bf16 [128, 65536] ----
__global__ __launch_bounds__(256) void combine_pool(
    const float* __restrict__ Tbase, const float* __restrict__ W,
    const float* __restrict__ bias, unsigned short* __restrict__ xpool) {
  int vp = blockIdx.x;                  // 2048 pooled groups
  __shared__ float tile[6][8][128];
  __shared__ float Wl[192];
  __shared__ float bl[32];
  for (int i = threadIdx.x; i < 192; i += 256) Wl[i] = W[i];
  if (threadIdx.x < 32) bl[threadIdx.x] = bias[threadIdx.x];
  for (int i = threadIdx.x; i < 6144; i += 256) {
    int k = i >> 10, rem = i & 1023, j = rem >> 7, b = rem & 127;
    tile[k][j][b] = Tbase[(size_t)k * 2097152 + (size_t)(vp * 8 + j) * BB + b];
  }
  __syncthreads();
  for (int p = threadIdx.x; p < 4096; p += 256) {
    int b = p >> 5, f = p & 31;
    float m = -1e30f;
    #pragma unroll
    for (int j = 0; j < 8; ++j) {
      float s = bl[f];
      #pragma unroll
      for (int k = 0; k < 6; ++k) s += tile[k][j][b] * Wl[f * 6 + k];
      m = fmaxf(m, s);
    }
    m = fmaxf(m, 0.f);
    xpool[(size_t)b * 65536 + vp * 32 + f] = f2bf(m);
  }
}

// ---- MFMA GEMM v3: block = 4 waves x 32 distinct cols = 128 cols, no intra-block split ----
// A bf16 [128,K]; W fp32 [N,K]; partial -> plane per blockIdx.y; direct -> bias(+relu), fp32/bf16 out.
// msplit: blockIdx.y selects row-half (MT=4) instead of K-chunk.
template<int MT>
__global__ __launch_bounds__(256) void gemm3(
    const unsigned short* __restrict__ A, const float* __restrict__ W,
    float* __restrict__ outP, unsigned short* __restrict__ outB,
    const float* __restrict__ bias, int K, int N, int Kchunk,
    int relu, int partial, int msplit) {
  int wid = threadIdx.x >> 6, lane = threadIdx.x & 63;
  int lr = lane & 15, lg = lane >> 4;
  int n0 = blockIdx.x * 128 + wid * 32;
  int row0 = msplit ? blockIdx.y * (MT * 16) : 0;
  int kbeg = msplit ? 0 : blockIdx.y * Kchunk;
  f32x4 acc[MT][2];
  #pragma unroll
  for (int mt = 0; mt < MT; ++mt) {
    acc[mt][0] = (f32x4){0.f, 0.f, 0.f, 0.f};
    acc[mt][1] = (f32x4){0.f, 0.f, 0.f, 0.f};
  }
  const unsigned short* Abase = A + (size_t)(row0 + lr) * K + lg * 8;
  const float* W0 = W + (size_t)(n0 + lr) * K + lg * 8;
  const float* W1 = W0 + (size_t)16 * K;
  for (int kb = kbeg; kb < kbeg + Kchunk; kb += 32) {
    bf16x8 af[MT];
    #pragma unroll
    for (int mt = 0; mt < MT; ++mt)
      af[mt] = *(const bf16x8*)(Abase + (size_t)mt * 16 * K + kb);
    f32x4 wa0 = ntload4(W0 + kb), wa1 = ntload4(W0 + kb + 4);
    f32x4 wb0 = ntload4(W1 + kb), wb1 = ntload4(W1 + kb + 4);
    bf16x8 b0, b1;
    b0[0] = (short)f2bf(wa0[0]); b0[1] = (short)f2bf(wa0[1]);
    b0[2] = (short)f2bf(wa0[2]); b0[3] = (short)f2bf(wa0[3]);
    b0[4] = (short)f2bf(wa1[0]); b0[5] = (short)f2bf(wa1[1]);
    b0[6] = (short)f2bf(wa1[2]); b0[7] = (short)f2bf(wa1[3]);
    b1[0] = (short)f2bf(wb0[0]); b1[1] = (short)f2bf(wb0[1]);
    b1[2] = (short)f2bf(wb0[2]); b1[3] = (short)f2bf(wb0[3]);
    b1[4] = (short)f2bf(wb1[0]); b1[5] = (short)f2bf(wb1[1]);
    b1[6] = (short)f2bf(wb1[2]); b1[7] = (short)f2bf(wb1[3]);
    #pragma unroll
    for (int mt = 0; mt < MT; ++mt) {
      acc[mt][0] = __builtin_amdgcn_mfma_f32_16x16x32_bf16(af[mt], b0, acc[mt][0], 0, 0, 0);
      acc[mt][1] = __builtin_amdgcn_mfma_f32_16x16x32_bf16(af[mt], b1, acc[mt][1], 0, 0, 0);
    }
  }
  if (partial) {
    float* P = outP + (size_t)blockIdx.y * 128 * (size_t)N;
    #pragma unroll
    for (int mt = 0; mt < MT; ++mt)
      #pragma unroll
      for (int nt = 0; nt < 2; ++nt) {
        int col = n0 + nt * 16 + lr;
        #pragma unroll
        for (int r = 0; r < 4; ++r) {
          int row = mt * 16 + lg * 4 + r;
          P[(size_t)row * N + col] = acc[mt][nt][r];
        }
      }
  } else {
    #pragma unroll
    for (int mt = 0; mt < MT; ++mt)
      #pragma unroll
      for (int nt = 0; nt < 2; ++nt) {
        int col = n0 + nt * 16 + lr;
        float bcol = bias[col];
        #pragma unroll
        for (int r = 0; r < 4; ++r) {
          int row = row0 + mt * 16 + lg * 4 + r;
          float v = acc[mt][nt][r] + bcol;
          if (relu) v = fmaxf(v, 0.f);
          if (outP) outP[(size_t)row * N + col] = v;
          if (outB) outB[(size_t)row * N + col] = f2bf(v);
        }
      }
  }
}

// ---- split-K reduce + bias + ReLU; optional fp32 and/or bf16 outputs ----
__global__ __launch_bounds__(256) void reduce2(
    const float* __restrict__ P, const float* __restrict__ bias,
    float* __restrict__ out, unsigned short* __restrict__ outb,
    int S, int total, int N, int relu) {
  int idx = blockIdx.x * 256 + threadIdx.x;
  if (idx >= total) return;
  float s = 0.f;
  for (int i = 0; i < S; ++i) s += P[(size_t)i * total + idx];
  float v = s + bias[idx % N];
  if (relu) v = fmaxf(v, 0.f);
  if (out) out[idx] = v;
  if (outb) outb[idx] = f2bf(v);
}

// ---- GCN4 meta-graph chain (batch-invariant): single block ----
__global__ __launch_bounds__(256) void g4_kernel(
    const float* __restrict__ xe_g, const float* __restrict__ Lmg_g,
    const float* __restrict__ W4, const float* __restrict__ b4,
    const float* __restrict__ Wg1, const float* __restrict__ bg1,
    const float* __restrict__ Wg2, const float* __restrict__ bg2,
    float* __restrict__ tail) {
  __shared__ float Lm[100], Tg[4][640], xc[320], xg96[96], h1[128];
  int t = threadIdx.x;
  for (int i = t; i < 640; i += 256) Tg[0][i] = xe_g[i];
  for (int i = t; i < 100; i += 256) Lm[i] = Lmg_g[i];
  __syncthreads();
  for (int i = t; i < 640; i += 256) {
    int v = i >> 6, f = i & 63; float s = 0.f;
    #pragma unroll
    for (int u = 0; u < 10; ++u) s += Lm[v * 10 + u] * Tg[0][u * 64 + f];
    Tg[1][i] = s;
  }
  __syncthreads();
  for (int kk = 2; kk < 4; ++kk) {
    for (int i = t; i < 640; i += 256) {
      int v = i >> 6, f = i & 63; float s = 0.f;
      #pragma unroll
      for (int u = 0; u < 10; ++u) s += Lm[v * 10 + u] * Tg[kk - 1][u * 64 + f];
      Tg[kk][i] = 2.f * s - Tg[kk - 2][i];
    }
    __syncthreads();
  }
  for (int i = t; i < 320; i += 256) {
    int v = i >> 5, fo = i & 31; float s = b4[fo];
    for (int fin = 0; fin < 64; ++fin)
      #pragma unroll
      for (int k = 0; k < 4; ++k) s += Tg[k][v * 64 + fin] * W4[fo * 256 + fin * 4 + k];
    xc[i] = fmaxf(s, 0.f);
  }
  __syncthreads();
  for (int i = t; i < 96; i += 256) {
    int g = i >> 5, fo = i & 31;
    xg96[i] = fmaxf(fmaxf(xc[(3 * g) * 32 + fo], xc[(3 * g + 1) * 32 + fo]),
                    xc[(3 * g + 2) * 32 + fo]);
  }
  __syncthreads();
  for (int o = t; o < 128; o += 256) {
    float s = bg1[o];
    for (int i2 = 0; i2 < 96; ++i2) s += xg96[i2] * Wg1[o * 96 + i2];
    h1[o] = fmaxf(s, 0.f);
  }
  __syncthreads();
  for (int o = t; o < 64; o += 256) {
    float s = bg2[o];
    for (int i2 = 0; i2 < 128; ++i2) s += h1[i2] * Wg2[o * 128 + i2];
    tail[o] = fmaxf(s, 0.f);
  }
}

// ---- wave-per-output dot + bias + ReLU (nn14 / nn24) ----
__global__ __launch_bounds__(64) void dot_relu_kernel(
    const float* __restrict__ x, const float* __restrict__ W,
    const float* __restrict__ bias, float* __restrict__ out, int K) {
  int o = blockIdx.x, lane = threadIdx.x;
  float a = 0.f;
  for (int i = lane; i < K; i += 64) a += x[i] * W[(size_t)o * K + i];
  #pragma unroll
  for (int s = 32; s > 0; s >>= 1) a += __shfl_down(a, s);
  if (lane == 0) out[o] = fmaxf(a + bias[o], 0.f);
}

// ---- fcsum + log_softmax: one block per batch row ----
__global__ __launch_bounds__(64) void fcsum_kernel(
    const float* __restrict__ hidden, const float* __restrict__ xnn2,
    const float* __restrict__ tail, const float* __restrict__ Ws,
    const float* __restrict__ bs, float* __restrict__ logp) {
  int b = blockIdx.x, lane = threadIdx.x;
  __shared__ float emb[896];
  for (int i = lane; i < 896; i += 64)
    emb[i] = (i < 512) ? hidden[b * 512 + i]
           : (i < 768) ? xnn2[b * 256 + (i - 512)]
                       : tail[i - 768];
  __syncthreads();
  float l[10];
  #pragma unroll
  for (int o = 0; o < 10; ++o) {
    float a = 0.f;
    for (int i = lane; i < 896; i += 64) a += emb[i] * Ws[o * 896 + i];
    #pragma unroll
    for (int s = 32; s > 0; s >>= 1) a += __shfl_down(a, s);
    l[o] = __shfl(a, 0) + bs[o];
  }
  float m = l[0];
  #pragma unroll
  for (int o = 1; o < 10; ++o) m = fmaxf(m, l[o]);
  float sum = 0.f;
  #pragma unroll
  for (int o = 0; o < 10; ++o) sum += expf(l[o] - m);
  float lse = m + logf(sum);
  #pragma unroll
  for (int o = 0; o < 10; ++o)
    if (lane == o) logp[b * 10 + o] = l[o] - lse;
}

extern "C" void kernel_launch(void* const* d_in, const int* in_sizes, int n_in,
                              void* d_out, int out_size, void* d_ws, size_t ws_size,
                              hipStream_t stream) {
  const float* x_in    = (const float*)d_in[0];
  const float* x_embed = (const float*)d_in[1];
  const int*   L_rows  = (const int*)d_in[3];
  const int*   L_cols  = (const int*)d_in[4];
  const float* L_vals  = (const float*)d_in[5];
  const float* L_mg    = (const float*)d_in[6];
  const float* cl1_W = (const float*)d_in[7],  *cl1_b = (const float*)d_in[8];
  const float* fc1_W = (const float*)d_in[9],  *fc1_b = (const float*)d_in[10];
  const float* fc2_W = (const float*)d_in[11], *fc2_b = (const float*)d_in[12];
  const float* fc3_W = (const float*)d_in[13], *fc3_b = (const float*)d_in[14];
  const float* nn1_W = (const float*)d_in[15], *nn1_b = (const float*)d_in[16];
  const float* nn2_W = (const float*)d_in[17], *nn2_b = (const float*)d_in[18];
  const float* cl4_W = (const float*)d_in[19], *cl4_b = (const float*)d_in[20];
  const float* fcg1_W = (const float*)d_in[21], *fcg1_b = (const float*)d_in[22];
  const float* fcg2_W = (const float*)d_in[23], *fcg2_b = (const float*)d_in[24];
  const float* nn14_W = (const float*)d_in[25], *nn14_b = (const float*)d_in[26];
  const float* nn24_W = (const float*)d_in[27], *nn24_b = (const float*)d_in[28];
  const float* fcsum_W = (const float*)d_in[29], *fcsum_b = (const float*)d_in[30];

  char* ws = (char*)d_ws;
  int* rowptr = (int*)(ws + WS_ROWPTR);
  unsigned short* xin16 = (unsigned short*)(ws + WS_XIN16);
  float* T = (float*)(ws + WS_T);              // 6 planes of 2097152 floats
  unsigned short* xpool = (unsigned short*)(ws + WS_XPOOL);
  unsigned short* Xb0 = (unsigned short*)(ws + WS_XB0);
  unsigned short* Xb1 = (unsigned short*)(ws + WS_XB1);
  unsigned short* xnn1b = (unsigned short*)(ws + WS_XNN1B);
  unsigned short* dec2 = (unsigned short*)(ws + WS_DEC2);
  float* xnn2 = (float*)(ws + WS_XNN2);
  unsigned short* hidB = (unsigned short*)(ws + WS_HIDB);
  float* n1 = (float*)(ws + WS_N1);
  float* tail = (float*)(ws + WS_TAIL);
  float* part1 = (float*)(ws + WS_PART1);
  float* part2 = (float*)(ws + WS_PART2);

  float* out0 = (float*)d_out;                 // x_decode_gae [128,16384]
  float* hidden = out0 + 2097152;              // x_hidden_gae [128,512]
  float* logp = out0 + 2097152 + 65536;        // [128,10]

  // tails first (independent of the big chain)
  g4_kernel<<<1, 256, 0, stream>>>(x_embed, L_mg, cl4_W, cl4_b, fcg1_W, fcg1_b,
                                   fcg2_W, fcg2_b, tail);
  dot_relu_kernel<<<256, 64, 0, stream>>>(x_embed, nn14_W, nn14_b, n1, 640);
  dot_relu_kernel<<<64, 64, 0, stream>>>(n1, nn24_W, nn24_b, tail + 64, 256);

  prep_kernel<<<2048, 256, 0, stream>>>(x_in, L_rows, rowptr, xin16);
  transpose_kernel<<<dim3(512, 4), dim3(32, 32), 0, stream>>>(x_in, T, Xb0);

  // Chebyshev recursion T1..T5 (gather source = bf16 shadow, state = fp32)
  spmm2<<<8192, 256, 0, stream>>>(rowptr, L_cols, L_vals, Xb0, nullptr,        T + 1 * 2097152, Xb1, 1.f);
  spmm2<<<8192, 256, 0, stream>>>(rowptr, L_cols, L_vals, Xb1, T,              T + 2 * 2097152, Xb0, 2.f);
  spmm2<<<8192, 256, 0, stream>>>(rowptr, L_cols, L_vals, Xb0, T + 1 * 2097152, T + 3 * 2097152, Xb1, 2.f);
  spmm2<<<8192, 256, 0, stream>>>(rowptr, L_cols, L_vals, Xb1, T + 2 * 2097152, T + 4 * 2097152, Xb0, 2.f);
  spmm2<<<8192, 256, 0, stream>>>(rowptr, L_cols, L_vals, Xb0, T + 3 * 2097152, T + 5 * 2097152, Xb1, 2.f);

  combine_pool<<<2048, 256, 0, stream>>>(T, cl1_W, cl1_b, xpool);

  // nn1: [128,16384] @ [512,16384]^T, split-K 64 planes
  gemm3<8><<<dim3(4, 64), 256, 0, stream>>>(xin16, nn1_W, part1, nullptr, nullptr,
                                            16384, 512, 256, 0, 1, 0);
  reduce2<<<256, 256, 0, stream>>>(part1, nn1_b, nullptr, xnn1b, 64, 65536, 512, 1);
  // nn2: [128,512] @ [256,512]^T direct
  gemm3<8><<<dim3(2, 1), 256, 0, stream>>>(xnn1b, nn2_W, xnn2, nullptr, nn2_b,
                                           512, 256, 512, 1, 0, 0);

  // fc1: [128,65536] @ [512,65536]^T, split-K 128 planes
  gemm3<8><<<dim3(4, 128), 256, 0, stream>>>(xpool, fc1_W, part2, nullptr, nullptr,
                                             65536, 512, 512, 0, 1, 0);
  reduce2<<<256, 256, 0, stream>>>(part2, fc1_b, hidden, hidB, 128, 65536, 512, 1);

  // fc2: [128,512] @ [512,512]^T direct -> bf16 dec2
  gemm3<8><<<dim3(4, 1), 256, 0, stream>>>(hidB, fc2_W, nullptr, dec2, fc2_b,
                                           512, 512, 512, 1, 0, 0);
  // fc3: [128,512] @ [16384,512]^T direct, M-split halves
  gemm3<4><<<dim3(128, 2), 256, 0, stream>>>(dec2, fc3_W, out0, nullptr, fc3_b,
                                             512, 16384, 512, 0, 0, 1);

  // final head
  fcsum_kernel<<<128, 64, 0, stream>>>(hidden, xnn2, tail, fcsum_W, fcsum_b, logp);
}

// Round 4
// 257.720 us; speedup vs baseline: 1.7345x; 1.7345x over previous
//
#include <hip/hip_runtime.h>
#include <hip/hip_bf16.h>

#define DG 16384
#define NNZ 262144
#define BB 128

typedef __attribute__((ext_vector_type(8))) short bf16x8;
typedef __attribute__((ext_vector_type(8))) unsigned short us8;
typedef __attribute__((ext_vector_type(4))) float f32x4;
typedef __attribute__((ext_vector_type(4))) unsigned short us4;
typedef __attribute__((ext_vector_type(2))) float f32x2;

// ---- workspace layout (bytes) ----
#define WS_ROWPTR 0            // 16385 ints
#define WS_XIN16  66048        // 128*16384 bf16
#define WS_T      4260352      // 6 fp32 planes of 16384*128 (partials alias after combine)
#define WS_XPOOL  54592000     // 128*65536 bf16
#define WS_XB0    71369216     // bf16 shadow plane A
#define WS_XB1    75563520     // bf16 shadow plane B
#define WS_XNN1B  79757824     // 128*512 bf16
#define WS_DEC2   79888896     // 128*512 bf16
#define WS_XNN2   80019968     // 128*256 fp32
#define WS_HIDB   80151040     // 128*512 bf16
#define WS_N1     80282112     // 256*4
#define WS_TAIL   80283136     // 128*4
#define PART_NN1_OFF 0         // relative to WS_T: 32 planes * 256KB = 8.4MB
#define PART_FC1_OFF 8388608   // 128 planes * 256KB = 33.5MB

__device__ __forceinline__ unsigned short f2bf(float f) {
  __hip_bfloat16 h = __float2bfloat16(f);
  return __builtin_bit_cast(unsigned short, h);
}
__device__ __forceinline__ float bflo(unsigned u) {
  return __builtin_bit_cast(float, u << 16);
}
__device__ __forceinline__ float bfhi(unsigned u) {
  return __builtin_bit_cast(float, u & 0xffff0000u);
}

// ================= fused setup: prep | transpose | nn14 | g4 =================
__device__ void prep_dev(const float* __restrict__ x_in, const int* __restrict__ rows,
                         int* __restrict__ rowptr, unsigned short* __restrict__ xin16,
                         int bid) {
  int idx = bid * 256 + threadIdx.x;
  if (idx <= DG) {
    int lo = 0, hi = NNZ;
    while (lo < hi) { int mid = (lo + hi) >> 1; if (rows[mid] < idx) lo = mid + 1; else hi = mid; }
    rowptr[idx] = lo;
  }
  f32x4 v = ((const f32x4*)x_in)[idx];
  us4 o; o[0] = f2bf(v[0]); o[1] = f2bf(v[1]); o[2] = f2bf(v[2]); o[3] = f2bf(v[3]);
  ((us4*)xin16)[idx] = o;
}

__device__ void transpose_dev(const float* __restrict__ x_in, float* __restrict__ T0,
                              unsigned short* __restrict__ Xb0, int id) {
  __shared__ float tl[32][33];
  int bx = id & 511, by = id >> 9;
  int v0 = bx * 32, b0 = by * 32;
  int tx = threadIdx.x & 31, ty0 = threadIdx.x >> 5;
  #pragma unroll
  for (int j = 0; j < 4; ++j) {
    int ty = ty0 + j * 8;
    tl[ty][tx] = x_in[(size_t)(b0 + ty) * DG + v0 + tx];
  }
  __syncthreads();
  #pragma unroll
  for (int j = 0; j < 4; ++j) {
    int ty = ty0 + j * 8;
    float v = tl[tx][ty];
    size_t o = (size_t)(v0 + ty) * BB + b0 + tx;
    T0[o] = v;
    Xb0[o] = f2bf(v);
  }
}

__device__ void dot4_dev(const float* __restrict__ x, const float* __restrict__ W,
                         const float* __restrict__ bias, float* __restrict__ out,
                         int K, int id) {
  int w = threadIdx.x >> 6, lane = threadIdx.x & 63;
  int o = id * 4 + w;
  float a = 0.f;
  for (int i = lane; i < K; i += 64) a += x[i] * W[(size_t)o * K + i];
  #pragma unroll
  for (int s = 32; s > 0; s >>= 1) a += __shfl_down(a, s);
  if (lane == 0) out[o] = fmaxf(a + bias[o], 0.f);
}

__device__ void g4_dev(const float* __restrict__ xe_g, const float* __restrict__ Lmg_g,
                       const float* __restrict__ W4, const float* __restrict__ b4,
                       const float* __restrict__ Wg1, const float* __restrict__ bg1,
                       const float* __restrict__ Wg2, const float* __restrict__ bg2,
                       float* __restrict__ tail) {
  __shared__ float Lm[100], Tg[4][640], xc[320], xg96[96], h1[128];
  int t = threadIdx.x;
  for (int i = t; i < 640; i += 256) Tg[0][i] = xe_g[i];
  for (int i = t; i < 100; i += 256) Lm[i] = Lmg_g[i];
  __syncthreads();
  for (int i = t; i < 640; i += 256) {
    int v = i >> 6, f = i & 63; float s = 0.f;
    #pragma unroll
    for (int u = 0; u < 10; ++u) s += Lm[v * 10 + u] * Tg[0][u * 64 + f];
    Tg[1][i] = s;
  }
  __syncthreads();
  for (int kk = 2; kk < 4; ++kk) {
    for (int i = t; i < 640; i += 256) {
      int v = i >> 6, f = i & 63; float s = 0.f;
      #pragma unroll
      for (int u = 0; u < 10; ++u) s += Lm[v * 10 + u] * Tg[kk - 1][u * 64 + f];
      Tg[kk][i] = 2.f * s - Tg[kk - 2][i];
    }
    __syncthreads();
  }
  for (int i = t; i < 320; i += 256) {
    int v = i >> 5, fo = i & 31; float s = b4[fo];
    for (int fin = 0; fin < 64; ++fin)
      #pragma unroll
      for (int k = 0; k < 4; ++k) s += Tg[k][v * 64 + fin] * W4[fo * 256 + fin * 4 + k];
    xc[i] = fmaxf(s, 0.f);
  }
  __syncthreads();
  for (int i = t; i < 96; i += 256) {
    int g = i >> 5, fo = i & 31;
    xg96[i] = fmaxf(fmaxf(xc[(3 * g) * 32 + fo], xc[(3 * g + 1) * 32 + fo]),
                    xc[(3 * g + 2) * 32 + fo]);
  }
  __syncthreads();
  for (int o = t; o < 128; o += 256) {
    float s = bg1[o];
    for (int i2 = 0; i2 < 96; ++i2) s += xg96[i2] * Wg1[o * 96 + i2];
    h1[o] = fmaxf(s, 0.f);
  }
  __syncthreads();
  for (int o = t; o < 64; o += 256) {
    float s = bg2[o];
    for (int i2 = 0; i2 < 128; ++i2) s += h1[i2] * Wg2[o * 128 + i2];
    tail[o] = fmaxf(s, 0.f);
  }
}

__global__ __launch_bounds__(256) void setup_kernel(
    const float* __restrict__ x_in, const int* __restrict__ rows,
    int* __restrict__ rowptr, unsigned short* __restrict__ xin16,
    float* __restrict__ T0, unsigned short* __restrict__ Xb0,
    const float* __restrict__ x_embed,
    const float* __restrict__ nn14_W, const float* __restrict__ nn14_b,
    float* __restrict__ n1,
    const float* __restrict__ Lmg, const float* __restrict__ W4,
    const float* __restrict__ b4, const float* __restrict__ Wg1,
    const float* __restrict__ bg1, const float* __restrict__ Wg2,
    const float* __restrict__ bg2, float* __restrict__ tail) {
  int bid = blockIdx.x;
  if (bid < 2048) prep_dev(x_in, rows, rowptr, xin16, bid);
  else if (bid < 4096) transpose_dev(x_in, T0, Xb0, bid - 2048);
  else if (bid < 4160) dot4_dev(x_embed, nn14_W, nn14_b, n1, 640, bid - 4096);
  else g4_dev(x_embed, Lmg, W4, b4, Wg1, bg1, Wg2, bg2, tail);
}

// ====== SpMM v3: 1 wave/row, ushort2 gathers, Chebyshev update ======
__global__ __launch_bounds__(256) void spmm3(
    const int* __restrict__ rowptr, const int* __restrict__ cols,
    const float* __restrict__ vals, const unsigned* __restrict__ X2,
    const float* __restrict__ Tprev, float* __restrict__ Tout,
    unsigned* __restrict__ Xbout, float scale) {
  int r = blockIdx.x * 4 + (threadIdx.x >> 6);
  int lane = threadIdx.x & 63;
  int e0 = rowptr[r], e1 = rowptr[r + 1];
  float a00 = 0.f, a01 = 0.f, a10 = 0.f, a11 = 0.f;
  int e = e0;
  for (; e + 4 <= e1; e += 4) {
    int c0 = cols[e], c1 = cols[e + 1], c2 = cols[e + 2], c3 = cols[e + 3];
    float v0 = vals[e], v1 = vals[e + 1], v2 = vals[e + 2], v3 = vals[e + 3];
    unsigned x0 = X2[c0 * 64 + lane], x1 = X2[c1 * 64 + lane];
    unsigned x2 = X2[c2 * 64 + lane], x3 = X2[c3 * 64 + lane];
    a00 += v0 * bflo(x0); a10 += v0 * bfhi(x0);
    a01 += v1 * bflo(x1); a11 += v1 * bfhi(x1);
    a00 += v2 * bflo(x2); a10 += v2 * bfhi(x2);
    a01 += v3 * bflo(x3); a11 += v3 * bfhi(x3);
  }
  for (; e < e1; ++e) {
    float v = vals[e]; unsigned x = X2[cols[e] * 64 + lane];
    a00 += v * bflo(x); a10 += v * bfhi(x);
  }
  float s0 = scale * (a00 + a01), s1 = scale * (a10 + a11);
  size_t o = (size_t)r * BB + lane * 2;
  if (Tprev) { f32x2 p = *(const f32x2*)(Tprev + o); s0 -= p[0]; s1 -= p[1]; }
  *(f32x2*)(Tout + o) = (f32x2){s0, s1};
  Xbout[(size_t)r * 64 + lane] = (unsigned)f2bf(s0) | ((unsigned)f2bf(s1) << 16);
}

// ====== combine + maxpool (+ nn24 piggyback) ======
__device__ void combine_dev(const float* __restrict__ Tbase, const float* __restrict__ W,
                            const float* __restrict__ bias, unsigned short* __restrict__ xpool,
                            int vp) {
  __shared__ float tile[6][8][128];
  __shared__ float Wl[192];
  __shared__ float bl[32];
  for (int i = threadIdx.x; i < 192; i += 256) Wl[i] = W[i];
  if (threadIdx.x < 32) bl[threadIdx.x] = bias[threadIdx.x];
  for (int i = threadIdx.x; i < 6144; i += 256) {
    int k = i >> 10, rem = i & 1023, j = rem >> 7, b = rem & 127;
    tile[k][j][b] = Tbase[(size_t)k * 2097152 + (size_t)(vp * 8 + j) * BB + b];
  }
  __syncthreads();
  for (int p = threadIdx.x; p < 4096; p += 256) {
    int b = p >> 5, f = p & 31;
    float m = -1e30f;
    #pragma unroll
    for (int j = 0; j < 8; ++j) {
      float s = bl[f];
      #pragma unroll
      for (int k = 0; k < 6; ++k) s += tile[k][j][b] * Wl[f * 6 + k];
      m = fmaxf(m, s);
    }
    m = fmaxf(m, 0.f);
    xpool[(size_t)b * 65536 + vp * 32 + f] = f2bf(m);
  }
}

__global__ __launch_bounds__(256) void combine_nn24(
    const float* __restrict__ Tbase, const float* __restrict__ W,
    const float* __restrict__ bias, unsigned short* __restrict__ xpool,
    const float* __restrict__ n1, const float* __restrict__ nn24_W,
    const float* __restrict__ nn24_b, float* __restrict__ tail64) {
  int bid = blockIdx.x;
  if (bid < 2048) combine_dev(Tbase, W, bias, xpool, bid);
  else dot4_dev(n1, nn24_W, nn24_b, tail64, 256, bid - 2048);
}

// ====== LDS-staged MFMA GEMM core ======
// A bf16 [128,K] row-major; W fp32 [N,K] row-major. Block: 4 waves, CN=NT*64 cols.
// Per stage: 64-wide K slab staged to LDS (XOR-swizzled 16B blocks), 2x K32 MFMA.
template<int NT>
__device__ void gemm_core(
    unsigned short* __restrict__ Alds,       // [128*64]
    unsigned short* __restrict__ Wlds,       // [CN*64]
    const unsigned short* __restrict__ A, const float* __restrict__ W,
    float* __restrict__ outP, unsigned short* __restrict__ outB,
    const float* __restrict__ bias, int K, int N, int Kchunk,
    int bx, int by, int relu, int partial) {
  const int CN = NT * 64;
  int t = threadIdx.x, w = t >> 6, lane = t & 63, lr = lane & 15, lg = lane >> 4;
  int n0 = bx * CN;
  int kbeg = by * Kchunk;
  f32x4 acc[8][NT];
  #pragma unroll
  for (int mt = 0; mt < 8; ++mt)
    #pragma unroll
    for (int nt = 0; nt < NT; ++nt)
      acc[mt][nt] = (f32x4){0.f, 0.f, 0.f, 0.f};
  int stages = Kchunk >> 6;
  for (int s = 0; s < stages; ++s) {
    int k0 = kbeg + s * 64;
    // A tile: 128 rows x 64 k (bf16), fully-coalesced 16B loads
    #pragma unroll
    for (int j = 0; j < 4; ++j) {
      int idx = j * 256 + t;
      int row = idx >> 3, kk = (idx & 7) * 8;
      us8 v = *(const us8*)(A + (size_t)row * K + k0 + kk);
      *(us8*)(Alds + row * 64 + (kk ^ ((row & 7) << 3))) = v;
    }
    // W tile: CN rows x 64 k fp32 -> bf16
    #pragma unroll
    for (int j = 0; j < NT * 4; ++j) {
      int idx = j * 256 + t;
      int wr = idx >> 4, kk = (idx & 15) * 4;
      f32x4 v = *(const f32x4*)(W + (size_t)(n0 + wr) * K + k0 + kk);
      us4 o; o[0] = f2bf(v[0]); o[1] = f2bf(v[1]); o[2] = f2bf(v[2]); o[3] = f2bf(v[3]);
      *(us4*)(Wlds + wr * 64 + (kk ^ ((wr & 7) << 3))) = o;
    }
    __syncthreads();
    #pragma unroll
    for (int h = 0; h < 2; ++h) {
      int k32 = h * 32;
      bf16x8 bfr[NT];
      #pragma unroll
      for (int nt = 0; nt < NT; ++nt) {
        int wrow = w * NT * 16 + nt * 16 + lr;
        bfr[nt] = *(const bf16x8*)(Wlds + wrow * 64 + ((k32 + lg * 8) ^ ((wrow & 7) << 3)));
      }
      #pragma unroll
      for (int mt = 0; mt < 8; ++mt) {
        int arow = mt * 16 + lr;
        bf16x8 af = *(const bf16x8*)(Alds + arow * 64 + ((k32 + lg * 8) ^ ((arow & 7) << 3)));
        #pragma unroll
        for (int nt = 0; nt < NT; ++nt)
          acc[mt][nt] = __builtin_amdgcn_mfma_f32_16x16x32_bf16(af, bfr[nt], acc[mt][nt], 0, 0, 0);
      }
    }
    __syncthreads();
  }
  if (partial) {
    float* P = outP + (size_t)by * 128 * (size_t)N;
    #pragma unroll
    for (int mt = 0; mt < 8; ++mt)
      #pragma unroll
      for (int nt = 0; nt < NT; ++nt) {
        int col = n0 + w * NT * 16 + nt * 16 + lr;
        #pragma unroll
        for (int r2 = 0; r2 < 4; ++r2) {
          int row = mt * 16 + lg * 4 + r2;
          P[(size_t)row * N + col] = acc[mt][nt][r2];
        }
      }
  } else {
    #pragma unroll
    for (int mt = 0; mt < 8; ++mt)
      #pragma unroll
      for (int nt = 0; nt < NT; ++nt) {
        int col = n0 + w * NT * 16 + nt * 16 + lr;
        float bc = bias[col];
        #pragma unroll
        for (int r2 = 0; r2 < 4; ++r2) {
          int row = mt * 16 + lg * 4 + r2;
          float v = acc[mt][nt][r2] + bc;
          if (relu) v = fmaxf(v, 0.f);
          if (outP) outP[(size_t)row * N + col] = v;
          if (outB) outB[(size_t)row * N + col] = f2bf(v);
        }
      }
  }
}

// ====== fused nn1+fc1 split-K partial gemm: 128 + 512 blocks ======
__global__ __launch_bounds__(256) void gemm_partials(
    const unsigned short* __restrict__ xin16, const float* __restrict__ nn1_W,
    const unsigned short* __restrict__ xpool, const float* __restrict__ fc1_W,
    float* __restrict__ pnn1, float* __restrict__ pfc1) {
  __shared__ unsigned short Alds[128 * 64];
  __shared__ unsigned short Wlds[128 * 64];
  int b = blockIdx.x;
  if (b < 128)
    gemm_core<2>(Alds, Wlds, xin16, nn1_W, pnn1, nullptr, nullptr,
                 16384, 512, 512, b & 3, b >> 2, 0, 1);
  else {
    b -= 128;
    gemm_core<2>(Alds, Wlds, xpool, fc1_W, pfc1, nullptr, nullptr,
                 65536, 512, 512, b & 3, b >> 2, 0, 1);
  }
}

// ====== fused split-K reduce: fc1 (S=128) + nn1 (S=32) ======
__global__ __launch_bounds__(256) void reduce_fused(
    const float* __restrict__ pfc1, const float* __restrict__ fc1_b,
    float* __restrict__ hidden, unsigned short* __restrict__ hidB,
    const float* __restrict__ pnn1, const float* __restrict__ nn1_b,
    unsigned short* __restrict__ xnn1b) {
  int b = blockIdx.x;
  if (b < 256) {
    int idx = b * 256 + threadIdx.x;
    float s = 0.f;
    for (int i = 0; i < 128; ++i) s += pfc1[(size_t)i * 65536 + idx];
    float v = fmaxf(s + fc1_b[idx & 511], 0.f);
    hidden[idx] = v;
    hidB[idx] = f2bf(v);
  } else {
    int idx = (b - 256) * 256 + threadIdx.x;
    float s = 0.f;
    for (int i = 0; i < 32; ++i) s += pnn1[(size_t)i * 65536 + idx];
    float v = fmaxf(s + nn1_b[idx & 511], 0.f);
    xnn1b[idx] = f2bf(v);
  }
}

// ====== fc2 + nn2 fused (direct, NT=1) ======
__global__ __launch_bounds__(256) void fc2nn2_kernel(
    const unsigned short* __restrict__ hidB, const float* __restrict__ fc2_W,
    const float* __restrict__ fc2_b, unsigned short* __restrict__ dec2,
    const unsigned short* __restrict__ xnn1b, const float* __restrict__ nn2_W,
    const float* __restrict__ nn2_b, float* __restrict__ xnn2) {
  __shared__ unsigned short Alds[128 * 64];
  __shared__ unsigned short Wlds[64 * 64];
  int b = blockIdx.x;
  if (b < 8)
    gemm_core<1>(Alds, Wlds, hidB, fc2_W, nullptr, dec2, fc2_b,
                 512, 512, 512, b, 0, 1, 0);
  else
    gemm_core<1>(Alds, Wlds, xnn1b, nn2_W, xnn2, nullptr, nn2_b,
                 512, 256, 512, b - 8, 0, 1, 0);
}

// ====== fc3 + fcsum head ======
__device__ void fcsum_dev(int id, const float* __restrict__ hidden,
                          const float* __restrict__ xnn2, const float* __restrict__ tail,
                          const float* __restrict__ Ws, const float* __restrict__ bs,
                          float* __restrict__ logp) {
  __shared__ float emb[4][896];
  int w = threadIdx.x >> 6, lane = threadIdx.x & 63;
  int b = id * 4 + w;
  for (int i = lane; i < 896; i += 64)
    emb[w][i] = (i < 512) ? hidden[b * 512 + i]
              : (i < 768) ? xnn2[b * 256 + (i - 512)]
                          : tail[i - 768];
  // same-wave LDS write->read: compiler inserts lgkmcnt wait; no barrier needed
  float l[10];
  #pragma unroll
  for (int o = 0; o < 10; ++o) {
    float a = 0.f;
    for (int i = lane; i < 896; i += 64) a += emb[w][i] * Ws[o * 896 + i];
    #pragma unroll
    for (int s = 32; s > 0; s >>= 1) a += __shfl_down(a, s);
    l[o] = __shfl(a, 0) + bs[o];
  }
  float m = l[0];
  #pragma unroll
  for (int o = 1; o < 10; ++o) m = fmaxf(m, l[o]);
  float sum = 0.f;
  #pragma unroll
  for (int o = 0; o < 10; ++o) sum += expf(l[o] - m);
  float lse = m + logf(sum);
  #pragma unroll
  for (int o = 0; o < 10; ++o)
    if (lane == o) logp[b * 10 + o] = l[o] - lse;
}

__global__ __launch_bounds__(256) void fc3_head(
    const unsigned short* __restrict__ dec2, const float* __restrict__ fc3_W,
    const float* __restrict__ fc3_b, float* __restrict__ out0,
    const float* __restrict__ hidden, const float* __restrict__ xnn2,
    const float* __restrict__ tail, const float* __restrict__ fcsum_W,
    const float* __restrict__ fcsum_b, float* __restrict__ logp) {
  __shared__ unsigned short Alds[128 * 64];
  __shared__ unsigned short Wlds[64 * 64];
  int b = blockIdx.x;
  if (b < 256)
    gemm_core<1>(Alds, Wlds, dec2, fc3_W, out0, nullptr, fc3_b,
                 512, 16384, 512, b, 0, 0, 0);
  else
    fcsum_dev(b - 256, hidden, xnn2, tail, fcsum_W, fcsum_b, logp);
}

extern "C" void kernel_launch(void* const* d_in, const int* in_sizes, int n_in,
                              void* d_out, int out_size, void* d_ws, size_t ws_size,
                              hipStream_t stream) {
  const float* x_in    = (const float*)d_in[0];
  const float* x_embed = (const float*)d_in[1];
  const int*   L_rows  = (const int*)d_in[3];
  const int*   L_cols  = (const int*)d_in[4];
  const float* L_vals  = (const float*)d_in[5];
  const float* L_mg    = (const float*)d_in[6];
  const float* cl1_W = (const float*)d_in[7],  *cl1_b = (const float*)d_in[8];
  const float* fc1_W = (const float*)d_in[9],  *fc1_b = (const float*)d_in[10];
  const float* fc2_W = (const float*)d_in[11], *fc2_b = (const float*)d_in[12];
  const float* fc3_W = (const float*)d_in[13], *fc3_b = (const float*)d_in[14];
  const float* nn1_W = (const float*)d_in[15], *nn1_b = (const float*)d_in[16];
  const float* nn2_W = (const float*)d_in[17], *nn2_b = (const float*)d_in[18];
  const float* cl4_W = (const float*)d_in[19], *cl4_b = (const float*)d_in[20];
  const float* fcg1_W = (const float*)d_in[21], *fcg1_b = (const float*)d_in[22];
  const float* fcg2_W = (const float*)d_in[23], *fcg2_b = (const float*)d_in[24];
  const float* nn14_W = (const float*)d_in[25], *nn14_b = (const float*)d_in[26];
  const float* nn24_W = (const float*)d_in[27], *nn24_b = (const float*)d_in[28];
  const float* fcsum_W = (const float*)d_in[29], *fcsum_b = (const float*)d_in[30];

  char* ws = (char*)d_ws;
  int* rowptr = (int*)(ws + WS_ROWPTR);
  unsigned short* xin16 = (unsigned short*)(ws + WS_XIN16);
  float* T = (float*)(ws + WS_T);              // 6 planes of 2097152 floats
  unsigned short* xpool = (unsigned short*)(ws + WS_XPOOL);
  unsigned short* Xb0 = (unsigned short*)(ws + WS_XB0);
  unsigned short* Xb1 = (unsigned short*)(ws + WS_XB1);
  unsigned short* xnn1b = (unsigned short*)(ws + WS_XNN1B);
  unsigned short* dec2 = (unsigned short*)(ws + WS_DEC2);
  float* xnn2 = (float*)(ws + WS_XNN2);
  unsigned short* hidB = (unsigned short*)(ws + WS_HIDB);
  float* n1 = (float*)(ws + WS_N1);
  float* tail = (float*)(ws + WS_TAIL);
  float* pnn1 = (float*)(ws + WS_T + PART_NN1_OFF);  // alias T (dead after combine)
  float* pfc1 = (float*)(ws + WS_T + PART_FC1_OFF);

  float* out0 = (float*)d_out;                 // x_decode_gae [128,16384]
  float* hidden = out0 + 2097152;              // x_hidden_gae [128,512]
  float* logp = out0 + 2097152 + 65536;        // [128,10]

  // L1: prep + transpose + nn14 + g4
  setup_kernel<<<4161, 256, 0, stream>>>(x_in, L_rows, rowptr, xin16, T, Xb0,
                                         x_embed, nn14_W, nn14_b, n1,
                                         L_mg, cl4_W, cl4_b, fcg1_W, fcg1_b,
                                         fcg2_W, fcg2_b, tail);

  // L2-L6: Chebyshev recursion (bf16 gather source, fp32 state)
  spmm3<<<4096, 256, 0, stream>>>(rowptr, L_cols, L_vals, (const unsigned*)Xb0,
                                  nullptr,          T + 1 * 2097152, (unsigned*)Xb1, 1.f);
  spmm3<<<4096, 256, 0, stream>>>(rowptr, L_cols, L_vals, (const unsigned*)Xb1,
                                  T,                T + 2 * 2097152, (unsigned*)Xb0, 2.f);
  spmm3<<<4096, 256, 0, stream>>>(rowptr, L_cols, L_vals, (const unsigned*)Xb0,
                                  T + 1 * 2097152,  T + 3 * 2097152, (unsigned*)Xb1, 2.f);
  spmm3<<<4096, 256, 0, stream>>>(rowptr, L_cols, L_vals, (const unsigned*)Xb1,
                                  T + 2 * 2097152,  T + 4 * 2097152, (unsigned*)Xb0, 2.f);
  spmm3<<<4096, 256, 0, stream>>>(rowptr, L_cols, L_vals, (const unsigned*)Xb0,
                                  T + 3 * 2097152,  T + 5 * 2097152, (unsigned*)Xb1, 2.f);

  // L7: combine+pool (+nn24)
  combine_nn24<<<2064, 256, 0, stream>>>(T, cl1_W, cl1_b, xpool,
                                         n1, nn24_W, nn24_b, tail + 64);

  // L8: nn1 (128 blocks) + fc1 (512 blocks) split-K partials
  gemm_partials<<<640, 256, 0, stream>>>(xin16, nn1_W, xpool, fc1_W, pnn1, pfc1);

  // L9: fused reduce -> hidden(+bf16), xnn1b
  reduce_fused<<<512, 256, 0, stream>>>(pfc1, fc1_b, hidden, hidB,
                                        pnn1, nn1_b, xnn1b);

  // L10: fc2 -> dec2 (bf16), nn2 -> xnn2 (fp32)
  fc2nn2_kernel<<<12, 256, 0, stream>>>(hidB, fc2_W, fc2_b, dec2,
                                        xnn1b, nn2_W, nn2_b, xnn2);

  // L11: fc3 -> x_decode_gae  +  fcsum/log_softmax -> logp
  fc3_head<<<288, 256, 0, stream>>>(dec2, fc3_W, fc3_b, out0,
                                    hidden, xnn2, tail, fcsum_W, fcsum_b, logp);
}